// Round 12
// baseline (66.931 us; speedup 1.0000x reference)
//
#include <hip/hip_runtime.h>
#include <hip/hip_bf16.h>

#define QLEN   1024
#define MLEN   1024
#define KLEN   2048
#define BATCH  8
#define DMODEL 1024
#define NCOLS  (BATCH * DMODEL)   // 8192
#define FTLEN  1025

#define BM 256
#define BN 128
#define BK 64
#define NT 20   // band for 256-row M-block: K in [m0, m0+1280), 20 tiles of 64

typedef __attribute__((ext_vector_type(4))) float f32x4;
typedef __attribute__((ext_vector_type(8))) short bf16x8;

typedef __attribute__((address_space(1))) const unsigned int as1_u32;
typedef __attribute__((address_space(3))) unsigned int as3_u32;

static __device__ __forceinline__ unsigned short f2bf(float f) {
    unsigned int u = __builtin_bit_cast(unsigned int, f);
    return (unsigned short)((u + 0x7fffu + ((u >> 16) & 1u)) >> 16);
}
static __device__ __forceinline__ float bf2f(unsigned short s) {
    return __builtin_bit_cast(float, (unsigned int)s << 16);
}
static __device__ __forceinline__ unsigned int packbf(float lo, float hi) {
    return (unsigned int)f2bf(lo) | ((unsigned int)f2bf(hi) << 16);
}

// ---------------------------------------------------------------------------
// Kernel 1: z<8  : cat = concat(mems, dec) (+ pos_emb), bf16, TRANSPOSED ->
//                  catT[n][k] (pair-packed u32 LDS transpose).
//           z==8 : fill W[m][k] = cos band matrix (fused launch).
// ---------------------------------------------------------------------------
__global__ __launch_bounds__(256) void prep_fused(
    const float* __restrict__ dec, const float* __restrict__ pos,
    const float* __restrict__ mems, const int* __restrict__ addp,
    unsigned short* __restrict__ catT, unsigned short* __restrict__ W)
{
    const int tid = threadIdx.x;
    if (blockIdx.z == 8) {
        const int bchunk = (blockIdx.y * 32 + blockIdx.x) * 4;
#pragma unroll
        for (int r = 0; r < 4; ++r) {
            const int idx = (bchunk + r) * 256 + tid;
            const int m = idx >> 9;
            const int k4 = (idx & 511) * 4;
            union { unsigned short s[4]; int2 v; } u;
#pragma unroll
            for (int j = 0; j < 4; ++j) {
                const int k = k4 + j;
                const int t = k - m;
                float w = 0.0f;
                if (t >= 0 && t < FTLEN) {
                    const int rr = (m * t) % FTLEN;
                    const float x = (float)rr * (1.0f / (float)FTLEN);  // revolutions
                    float c;
                    asm("v_cos_f32 %0, %1" : "=v"(c) : "v"(x));
                    w = c * 0.03123475237772121f;   // 1/sqrt(1025)
                }
                u.s[j] = f2bf(w);
            }
            *reinterpret_cast<int2*>(&W[(size_t)m * KLEN + k4]) = u.v;
        }
        return;
    }

    __shared__ unsigned int T2[32 * 68];   // 8704 B, stride 68 u32
    const int lt = blockIdx.x, dt = blockIdx.y, b = blockIdx.z;
    const int l0 = lt * 64, d0 = dt * 64;
    const int add_position = addp[0];

    const int dloc  = (tid & 15) * 4;   // 0..60
    const int lhalf = tid >> 4;         // 0..15

    float4 vc[2][2];
#pragma unroll
    for (int p = 0; p < 2; ++p)
#pragma unroll
        for (int jl = 0; jl < 2; ++jl) {
            const int l = l0 + p * 32 + lhalf * 2 + jl;
            const float* src = (l < MLEN)
                ? (mems + (size_t)l * NCOLS + b * DMODEL + d0 + dloc)
                : (dec + (size_t)(l - MLEN) * NCOLS + b * DMODEL + d0 + dloc);
            vc[p][jl] = *reinterpret_cast<const float4*>(src);
        }
    if (add_position) {
#pragma unroll
        for (int p = 0; p < 2; ++p)
#pragma unroll
            for (int jl = 0; jl < 2; ++jl) {
                const int l = l0 + p * 32 + lhalf * 2 + jl;
                float4 pv = *reinterpret_cast<const float4*>(
                    pos + (size_t)l * DMODEL + d0 + dloc);
                vc[p][jl].x += pv.x; vc[p][jl].y += pv.y;
                vc[p][jl].z += pv.z; vc[p][jl].w += pv.w;
            }
    }
#pragma unroll
    for (int p = 0; p < 2; ++p) {
        const int lp = p * 16 + lhalf;   // 0..31
        uint4 w;
        w.x = packbf(vc[p][0].x, vc[p][1].x);
        w.y = packbf(vc[p][0].y, vc[p][1].y);
        w.z = packbf(vc[p][0].z, vc[p][1].z);
        w.w = packbf(vc[p][0].w, vc[p][1].w);
        *reinterpret_cast<uint4*>(&T2[lp * 68 + dloc]) = w;
    }
    __syncthreads();
    const int d = tid >> 2;              // 0..63
    const size_t n = (size_t)b * DMODEL + d0 + d;
#pragma unroll
    for (int q = 0; q < 2; ++q) {
        const int c8 = (tid & 3) + 4 * q;    // 0..7
        uint4 o;
        o.x = T2[(c8 * 4 + 0) * 68 + d];
        o.y = T2[(c8 * 4 + 1) * 68 + d];
        o.z = T2[(c8 * 4 + 2) * 68 + d];
        o.w = T2[(c8 * 4 + 3) * 68 + d];
        *reinterpret_cast<uint4*>(&catT[n * KLEN + l0 + c8 * 8]) = o;
    }
}

// ---------------------------------------------------------------------------
// Kernel 2: banded GEMM v11 — wave-tile 128x64 (1.7x MFMA:LDS ratio).
// BM=256 x BN=128, 4 waves (2m x 2n), grid 4x64 = 256 = 1/CU.
// Same minimal sync as v9/v10: one s_barrier + one counted vmcnt per K-tile,
// compiler-interleaved body, T2 both-sides XOR swizzle (linear gload_lds dest
// + pre-swizzled global src + XOR'd reads), triple-buffered LDS (3 x 48KB),
// setprio around MFMA clusters. 12 staging loads/wave/tile -> vmcnt(12).
// Epilogue fuses residual: x = bf16(dec + acc/sqrt(2048)).
// ---------------------------------------------------------------------------
__global__ __launch_bounds__(256, 1) void gemm_band11(
    const unsigned short* __restrict__ W,     // [1024][2048]
    const unsigned short* __restrict__ catT,  // [8192][2048]
    const float* __restrict__ dec,            // [1024][8192]
    unsigned short* __restrict__ xout)        // bf16 [1024][8192]
{
    __shared__ unsigned short Alds[3][BM * BK];   // 3 x 32KB
    __shared__ unsigned short Blds[3][BN * BK];   // 3 x 16KB  (total 144KB)

    const int tid = threadIdx.x;
    const int wave = tid >> 6, lane = tid & 63;

    // XCD swizzle: xcd = bid&7 gets n_idx in [xcd*8, xcd*8+8), all 4 m.
    const int bid = blockIdx.x;
    const int xcd = bid & 7;
    const int kk = bid >> 3;              // 0..31
    const int m_idx = kk >> 3;            // 0..3
    const int n_idx = xcd * 8 + (kk & 7); // 0..63
    const int m0 = m_idx * BM, n0 = n_idx * BN;
    const int wm = wave >> 1, wn = wave & 1;   // 2m x 2n wave grid

    f32x4 acc[8][4];
#pragma unroll
    for (int i = 0; i < 8; ++i)
#pragma unroll
        for (int j = 0; j < 4; ++j)
            acc[i][j] = (f32x4){0.f, 0.f, 0.f, 0.f};

    const int srow = tid >> 3;           // 0..31
    const int scol = (((tid & 7) ^ ((tid >> 3) & 7)) * 8);  // pre-swizzled src col
    const int fr = lane & 15;
    const int kg = lane >> 4;
    const int rswz = (fr & 7) * 8;       // read-side XOR (elements)

    // A: 8 insts x 32 rows; B: 4 insts x 32 rows. 12 loads/wave/tile.
#define STAGE_A(S, T, P) do {                                                   \
    const int k0_ = m0 + (T) * BK;                                              \
    const int row = (P) * 32 + srow;                                            \
    __builtin_amdgcn_global_load_lds(                                           \
        (as1_u32*)(const void*)(W + (size_t)(m0 + row) * KLEN + k0_ + scol),    \
        (as3_u32*)(void*)(&Alds[S][row * BK + scol]), 16, 0, 0);                \
} while (0)
#define STAGE_B(S, T, P) do {                                                   \
    const int k0_ = m0 + (T) * BK;                                              \
    const int row = (P) * 32 + srow;                                            \
    __builtin_amdgcn_global_load_lds(                                           \
        (as1_u32*)(const void*)(catT + (size_t)(n0 + row) * KLEN + k0_ + scol), \
        (as3_u32*)(void*)(&Blds[S][row * BK + scol]), 16, 0, 0);                \
} while (0)
#define STAGE_ALL(S, T) do {                                                    \
    STAGE_A(S, T, 0); STAGE_A(S, T, 1); STAGE_A(S, T, 2); STAGE_A(S, T, 3);     \
    STAGE_A(S, T, 4); STAGE_A(S, T, 5); STAGE_A(S, T, 6); STAGE_A(S, T, 7);     \
    STAGE_B(S, T, 0); STAGE_B(S, T, 1); STAGE_B(S, T, 2); STAGE_B(S, T, 3);     \
} while (0)

    STAGE_ALL(0, 0);   // 12 outstanding
    STAGE_ALL(1, 1);   // 24 outstanding

    for (int t = 0; t < NT; ++t) {
        // retire tile t's 12 loads; keep tile t+1's 12 in flight
        if (t == NT - 1)
            asm volatile("s_waitcnt vmcnt(0)" ::: "memory");
        else
            asm volatile("s_waitcnt vmcnt(12)" ::: "memory");
        __builtin_amdgcn_s_barrier();

        const unsigned short* Ab = Alds[t % 3];
        const unsigned short* Bb = Blds[t % 3];
        const int s2 = (t + 2) % 3;
        const bool pf = (t + 2 < NT);

        // ---------------- phase 0 (ks = 0) ----------------
        {
            bf16x8 a[8], b[4];
#pragma unroll
            for (int f = 0; f < 8; ++f)
                a[f] = *reinterpret_cast<const bf16x8*>(
                    Ab + (wm * 128 + f * 16 + fr) * BK + ((kg * 8) ^ rswz));
#pragma unroll
            for (int f = 0; f < 4; ++f)
                b[f] = *reinterpret_cast<const bf16x8*>(
                    Bb + (wn * 64 + f * 16 + fr) * BK + ((kg * 8) ^ rswz));
            if (pf) {
                STAGE_A(s2, t + 2, 0); STAGE_A(s2, t + 2, 1);
                STAGE_A(s2, t + 2, 2); STAGE_A(s2, t + 2, 3);
                STAGE_B(s2, t + 2, 0); STAGE_B(s2, t + 2, 1);
            }
            __builtin_amdgcn_s_setprio(1);
#pragma unroll
            for (int fm = 0; fm < 8; ++fm)
#pragma unroll
                for (int fn = 0; fn < 4; ++fn)
                    acc[fm][fn] = __builtin_amdgcn_mfma_f32_16x16x32_bf16(
                        a[fm], b[fn], acc[fm][fn], 0, 0, 0);
            __builtin_amdgcn_s_setprio(0);
        }
        // ---------------- phase 1 (ks = 1) ----------------
        {
            bf16x8 a[8], b[4];
#pragma unroll
            for (int f = 0; f < 8; ++f)
                a[f] = *reinterpret_cast<const bf16x8*>(
                    Ab + (wm * 128 + f * 16 + fr) * BK + ((32 + kg * 8) ^ rswz));
#pragma unroll
            for (int f = 0; f < 4; ++f)
                b[f] = *reinterpret_cast<const bf16x8*>(
                    Bb + (wn * 64 + f * 16 + fr) * BK + ((32 + kg * 8) ^ rswz));
            if (pf) {
                STAGE_A(s2, t + 2, 4); STAGE_A(s2, t + 2, 5);
                STAGE_A(s2, t + 2, 6); STAGE_A(s2, t + 2, 7);
                STAGE_B(s2, t + 2, 2); STAGE_B(s2, t + 2, 3);
            }
            __builtin_amdgcn_s_setprio(1);
#pragma unroll
            for (int fm = 0; fm < 8; ++fm)
#pragma unroll
                for (int fn = 0; fn < 4; ++fn)
                    acc[fm][fn] = __builtin_amdgcn_mfma_f32_16x16x32_bf16(
                        a[fm], b[fn], acc[fm][fn], 0, 0, 0);
            __builtin_amdgcn_s_setprio(0);
        }
    }
#undef STAGE_ALL
#undef STAGE_A
#undef STAGE_B

    // epilogue: x = bf16(dec + acc/sqrt(2048)); C/D: col=lane&15, row=(lane>>4)*4+j
    const float inv = 0.022097086912079612f;  // 1/sqrt(2048)
    const int col16 = lane & 15, rquad = lane >> 4;
#pragma unroll
    for (int fm = 0; fm < 8; ++fm)
#pragma unroll
        for (int fn = 0; fn < 4; ++fn)
#pragma unroll
            for (int j = 0; j < 4; ++j) {
                const int m = m0 + wm * 128 + fm * 16 + rquad * 4 + j;
                const int n = n0 + wn * 64 + fn * 16 + col16;
                const size_t o = (size_t)m * NCOLS + n;
                xout[o] = f2bf(dec[o] + acc[fm][fn][j] * inv);
            }
}

// ---------------------------------------------------------------------------
// Kernel 3: out = LayerNorm(x) over d=1024 per (m,b) row. x bf16 (residual
// already applied), out f32. 48 MB traffic.
// ---------------------------------------------------------------------------
__global__ __launch_bounds__(256) void layernorm_rows(
    const unsigned short* __restrict__ x,
    const float* __restrict__ gamma, const float* __restrict__ beta,
    float* __restrict__ out)
{
    __shared__ float ps[4], pq[4];
    const int row = blockIdx.x;
    const int tid = threadIdx.x;
    const size_t base = (size_t)row * DMODEL + tid * 4;
    ushort4 u = *reinterpret_cast<const ushort4*>(x + base);
    float vx = bf2f(u.x), vy = bf2f(u.y), vz = bf2f(u.z), vw = bf2f(u.w);
    float s  = vx + vy + vz + vw;
    float sq = vx * vx + vy * vy + vz * vz + vw * vw;
    for (int off = 32; off > 0; off >>= 1) {
        s  += __shfl_down(s, off);
        sq += __shfl_down(sq, off);
    }
    const int wave = tid >> 6, lane = tid & 63;
    if (lane == 0) { ps[wave] = s; pq[wave] = sq; }
    __syncthreads();
    if (tid == 0) {
        float ts = ps[0] + ps[1] + ps[2] + ps[3];
        float tq = pq[0] + pq[1] + pq[2] + pq[3];
        float mu = ts * (1.0f / DMODEL);
        float var = tq * (1.0f / DMODEL) - mu * mu;
        ps[0] = mu;
        pq[0] = rsqrtf(var + 1e-5f);
    }
    __syncthreads();
    const float mu = ps[0], rs = pq[0];
    float4 g  = *reinterpret_cast<const float4*>(gamma + tid * 4);
    float4 be = *reinterpret_cast<const float4*>(beta + tid * 4);
    float4 o;
    o.x = g.x * (vx - mu) * rs + be.x;
    o.y = g.y * (vy - mu) * rs + be.y;
    o.z = g.z * (vz - mu) * rs + be.z;
    o.w = g.w * (vw - mu) * rs + be.w;
    *reinterpret_cast<float4*>(out + base) = o;
}

extern "C" void kernel_launch(void* const* d_in, const int* in_sizes, int n_in,
                              void* d_out, int out_size, void* d_ws, size_t ws_size,
                              hipStream_t stream)
{
    const float* dec   = (const float*)d_in[0];
    const float* pos   = (const float*)d_in[1];
    const float* mems  = (const float*)d_in[2];
    const float* gamma = (const float*)d_in[3];
    const float* beta  = (const float*)d_in[4];
    const int*   addp  = (const int*)d_in[5];
    float* out = (float*)d_out;

    // ws: catT bf16 [8192][2048] (32MB) | W bf16 [1024][2048] (4MB) | x bf16 (16MB)
    unsigned short* catT = (unsigned short*)d_ws;
    unsigned short* Wmat = catT + (size_t)NCOLS * KLEN;
    unsigned short* x    = Wmat + (size_t)QLEN * KLEN;

    prep_fused<<<dim3(32, 16, 9), 256, 0, stream>>>(dec, pos, mems, addp, catT, Wmat);
    gemm_band11<<<256, 256, 0, stream>>>(Wmat, catT, dec, x);
    layernorm_rows<<<8192, 256, 0, stream>>>(x, gamma, beta, out);
}

// Round 13
// 64.525 us; speedup vs baseline: 1.0373x; 1.0373x over previous
//
#include <hip/hip_runtime.h>
#include <hip/hip_bf16.h>

#define QLEN   1024
#define MLEN   1024
#define KLEN   2048
#define BATCH  8
#define DMODEL 1024
#define NCOLS  (BATCH * DMODEL)   // 8192
#define FTLEN  1025

#define BM 128
#define BN 256
#define BK 64
#define NT 18   // band: K in [m0, m0+1152), 18 tiles of 64

typedef __attribute__((ext_vector_type(4))) float f32x4;
typedef __attribute__((ext_vector_type(8))) short bf16x8;

typedef __attribute__((address_space(1))) const unsigned int as1_u32;
typedef __attribute__((address_space(3))) unsigned int as3_u32;

static __device__ __forceinline__ unsigned short f2bf(float f) {
    unsigned int u = __builtin_bit_cast(unsigned int, f);
    return (unsigned short)((u + 0x7fffu + ((u >> 16) & 1u)) >> 16);
}
static __device__ __forceinline__ float bf2f(unsigned short s) {
    return __builtin_bit_cast(float, (unsigned int)s << 16);
}
static __device__ __forceinline__ unsigned int packbf(float lo, float hi) {
    return (unsigned int)f2bf(lo) | ((unsigned int)f2bf(hi) << 16);
}

// ---------------------------------------------------------------------------
// Kernel 1: z<8  : cat = concat(mems, dec) (+ pos_emb), bf16, TRANSPOSED ->
//                  catT[n][k] (pair-packed u32 LDS transpose).
//           z==8 : fill W[m][k] = cos band matrix (fused launch).
// ---------------------------------------------------------------------------
__global__ __launch_bounds__(256) void prep_fused(
    const float* __restrict__ dec, const float* __restrict__ pos,
    const float* __restrict__ mems, const int* __restrict__ addp,
    unsigned short* __restrict__ catT, unsigned short* __restrict__ W)
{
    const int tid = threadIdx.x;
    if (blockIdx.z == 8) {
        const int bchunk = (blockIdx.y * 32 + blockIdx.x) * 4;
#pragma unroll
        for (int r = 0; r < 4; ++r) {
            const int idx = (bchunk + r) * 256 + tid;
            const int m = idx >> 9;
            const int k4 = (idx & 511) * 4;
            union { unsigned short s[4]; int2 v; } u;
#pragma unroll
            for (int j = 0; j < 4; ++j) {
                const int k = k4 + j;
                const int t = k - m;
                float w = 0.0f;
                if (t >= 0 && t < FTLEN) {
                    const int rr = (m * t) % FTLEN;
                    const float x = (float)rr * (1.0f / (float)FTLEN);  // revolutions
                    float c;
                    asm("v_cos_f32 %0, %1" : "=v"(c) : "v"(x));
                    w = c * 0.03123475237772121f;   // 1/sqrt(1025)
                }
                u.s[j] = f2bf(w);
            }
            *reinterpret_cast<int2*>(&W[(size_t)m * KLEN + k4]) = u.v;
        }
        return;
    }

    __shared__ unsigned int T2[32 * 68];   // 8704 B, stride 68 u32
    const int lt = blockIdx.x, dt = blockIdx.y, b = blockIdx.z;
    const int l0 = lt * 64, d0 = dt * 64;
    const int add_position = addp[0];

    const int dloc  = (tid & 15) * 4;   // 0..60
    const int lhalf = tid >> 4;         // 0..15

    float4 vc[2][2];
#pragma unroll
    for (int p = 0; p < 2; ++p)
#pragma unroll
        for (int jl = 0; jl < 2; ++jl) {
            const int l = l0 + p * 32 + lhalf * 2 + jl;
            const float* src = (l < MLEN)
                ? (mems + (size_t)l * NCOLS + b * DMODEL + d0 + dloc)
                : (dec + (size_t)(l - MLEN) * NCOLS + b * DMODEL + d0 + dloc);
            vc[p][jl] = *reinterpret_cast<const float4*>(src);
        }
    if (add_position) {
#pragma unroll
        for (int p = 0; p < 2; ++p)
#pragma unroll
            for (int jl = 0; jl < 2; ++jl) {
                const int l = l0 + p * 32 + lhalf * 2 + jl;
                float4 pv = *reinterpret_cast<const float4*>(
                    pos + (size_t)l * DMODEL + d0 + dloc);
                vc[p][jl].x += pv.x; vc[p][jl].y += pv.y;
                vc[p][jl].z += pv.z; vc[p][jl].w += pv.w;
            }
    }
#pragma unroll
    for (int p = 0; p < 2; ++p) {
        const int lp = p * 16 + lhalf;   // 0..31
        uint4 w;
        w.x = packbf(vc[p][0].x, vc[p][1].x);
        w.y = packbf(vc[p][0].y, vc[p][1].y);
        w.z = packbf(vc[p][0].z, vc[p][1].z);
        w.w = packbf(vc[p][0].w, vc[p][1].w);
        *reinterpret_cast<uint4*>(&T2[lp * 68 + dloc]) = w;
    }
    __syncthreads();
    const int d = tid >> 2;              // 0..63
    const size_t n = (size_t)b * DMODEL + d0 + d;
#pragma unroll
    for (int q = 0; q < 2; ++q) {
        const int c8 = (tid & 3) + 4 * q;    // 0..7
        uint4 o;
        o.x = T2[(c8 * 4 + 0) * 68 + d];
        o.y = T2[(c8 * 4 + 1) * 68 + d];
        o.z = T2[(c8 * 4 + 2) * 68 + d];
        o.w = T2[(c8 * 4 + 3) * 68 + d];
        *reinterpret_cast<uint4*>(&catT[n * KLEN + l0 + c8 * 8]) = o;
    }
}

// ---------------------------------------------------------------------------
// Kernel 2: banded GEMM v12 — R11's minimal-sync loop (one s_barrier + one
// counted vmcnt(6) per K-tile, compiler-interleaved body) with the STAGE(t+2)
// issue hoisted to the tile top: loads get ~a full extra phase in flight
// before their deadline, phase bodies are pure ds_read+MFMA.
// Epilogue fuses residual: x = bf16(dec + acc/sqrt(2048)).
// ---------------------------------------------------------------------------
__global__ __launch_bounds__(512) void gemm_band12(
    const unsigned short* __restrict__ W,     // [1024][2048]
    const unsigned short* __restrict__ catT,  // [8192][2048]
    const float* __restrict__ dec,            // [1024][8192]
    unsigned short* __restrict__ xout)        // bf16 [1024][8192]
{
    __shared__ unsigned short Alds[3][BM * BK];   // 3 x 16KB
    __shared__ unsigned short Blds[3][BN * BK];   // 3 x 32KB  (total 144KB)

    const int tid = threadIdx.x;
    const int wave = tid >> 6, lane = tid & 63;

    const int bid = blockIdx.x;
    const int xcd = bid & 7;
    const int kk = bid >> 3;              // 0..31
    const int m_idx = kk >> 2;            // 0..7
    const int n_idx = xcd * 4 + (kk & 3); // 0..31
    const int m0 = m_idx * BM, n0 = n_idx * BN;
    const int wm = wave >> 2, wn = wave & 3;   // 2 x 4 wave grid

    f32x4 acc[4][4];
    for (int i = 0; i < 4; ++i)
        for (int j = 0; j < 4; ++j)
            acc[i][j] = (f32x4){0.f, 0.f, 0.f, 0.f};

    const int srow = tid >> 3;           // 0..63
    const int scol = (((tid & 7) ^ ((tid >> 3) & 7)) * 8);  // pre-swizzled src col
    const int fr = lane & 15;
    const int kg = lane >> 4;
    const int rswz = (fr & 7) * 8;       // read-side XOR (elements)

#define STAGE_LOAD_A(S, T, P) do {                                              \
    const int k0_ = m0 + (T) * BK;                                              \
    const int row = (P) * 64 + srow;                                            \
    __builtin_amdgcn_global_load_lds(                                           \
        (as1_u32*)(const void*)(W + (size_t)(m0 + row) * KLEN + k0_ + scol),    \
        (as3_u32*)(void*)(&Alds[S][row * BK + scol]), 16, 0, 0);                \
} while (0)
#define STAGE_LOAD_B(S, T, P) do {                                              \
    const int k0_ = m0 + (T) * BK;                                              \
    const int row = (P) * 64 + srow;                                            \
    __builtin_amdgcn_global_load_lds(                                           \
        (as1_u32*)(const void*)(catT + (size_t)(n0 + row) * KLEN + k0_ + scol), \
        (as3_u32*)(void*)(&Blds[S][row * BK + scol]), 16, 0, 0);                \
} while (0)
#define STAGE_ALL(S, T) do {                                                    \
    STAGE_LOAD_A(S, T, 0); STAGE_LOAD_A(S, T, 1);                               \
    STAGE_LOAD_B(S, T, 0); STAGE_LOAD_B(S, T, 1);                               \
    STAGE_LOAD_B(S, T, 2); STAGE_LOAD_B(S, T, 3);                               \
} while (0)

    STAGE_ALL(0, 0);
    STAGE_ALL(1, 1);

    for (int t = 0; t < NT; ++t) {
        if (t == NT - 1)
            asm volatile("s_waitcnt vmcnt(0)" ::: "memory");
        else
            asm volatile("s_waitcnt vmcnt(6)" ::: "memory");
        __builtin_amdgcn_s_barrier();

        const unsigned short* Ab = Alds[t % 3];
        const unsigned short* Bb = Blds[t % 3];

        // stage t+2 up front: maximal in-flight time before its deadline
        if (t + 2 < NT) STAGE_ALL((t + 2) % 3, t + 2);

        // ---------------- phase 0 (ks = 0) ----------------
        {
            bf16x8 a[4], b[4];
#pragma unroll
            for (int f = 0; f < 4; ++f)
                a[f] = *reinterpret_cast<const bf16x8*>(
                    Ab + (wm * 64 + f * 16 + fr) * BK + ((kg * 8) ^ rswz));
#pragma unroll
            for (int f = 0; f < 4; ++f)
                b[f] = *reinterpret_cast<const bf16x8*>(
                    Bb + (wn * 64 + f * 16 + fr) * BK + ((kg * 8) ^ rswz));
            __builtin_amdgcn_s_setprio(1);
#pragma unroll
            for (int fm = 0; fm < 4; ++fm)
#pragma unroll
                for (int fn = 0; fn < 4; ++fn)
                    acc[fm][fn] = __builtin_amdgcn_mfma_f32_16x16x32_bf16(
                        a[fm], b[fn], acc[fm][fn], 0, 0, 0);
            __builtin_amdgcn_s_setprio(0);
        }
        // ---------------- phase 1 (ks = 1) ----------------
        {
            bf16x8 a[4], b[4];
#pragma unroll
            for (int f = 0; f < 4; ++f)
                a[f] = *reinterpret_cast<const bf16x8*>(
                    Ab + (wm * 64 + f * 16 + fr) * BK + ((32 + kg * 8) ^ rswz));
#pragma unroll
            for (int f = 0; f < 4; ++f)
                b[f] = *reinterpret_cast<const bf16x8*>(
                    Bb + (wn * 64 + f * 16 + fr) * BK + ((32 + kg * 8) ^ rswz));
            __builtin_amdgcn_s_setprio(1);
#pragma unroll
            for (int fm = 0; fm < 4; ++fm)
#pragma unroll
                for (int fn = 0; fn < 4; ++fn)
                    acc[fm][fn] = __builtin_amdgcn_mfma_f32_16x16x32_bf16(
                        a[fm], b[fn], acc[fm][fn], 0, 0, 0);
            __builtin_amdgcn_s_setprio(0);
        }
    }
#undef STAGE_ALL
#undef STAGE_LOAD_A
#undef STAGE_LOAD_B

    // epilogue: x = bf16(dec + acc/sqrt(2048)); C/D: col=lane&15, row=(lane>>4)*4+j
    const float inv = 0.022097086912079612f;  // 1/sqrt(2048)
    const int col16 = lane & 15, rquad = lane >> 4;
#pragma unroll
    for (int fm = 0; fm < 4; ++fm)
#pragma unroll
        for (int fn = 0; fn < 4; ++fn)
#pragma unroll
            for (int j = 0; j < 4; ++j) {
                const int m = m0 + wm * 64 + fm * 16 + rquad * 4 + j;
                const int n = n0 + wn * 64 + fn * 16 + col16;
                const size_t o = (size_t)m * NCOLS + n;
                xout[o] = f2bf(dec[o] + acc[fm][fn][j] * inv);
            }
}

// ---------------------------------------------------------------------------
// Kernel 3: out = LayerNorm(x) over d=1024 per (m,b) row. x bf16 (residual
// already applied), out f32. 48 MB traffic.
// ---------------------------------------------------------------------------
__global__ __launch_bounds__(256) void layernorm_rows(
    const unsigned short* __restrict__ x,
    const float* __restrict__ gamma, const float* __restrict__ beta,
    float* __restrict__ out)
{
    __shared__ float ps[4], pq[4];
    const int row = blockIdx.x;
    const int tid = threadIdx.x;
    const size_t base = (size_t)row * DMODEL + tid * 4;
    ushort4 u = *reinterpret_cast<const ushort4*>(x + base);
    float vx = bf2f(u.x), vy = bf2f(u.y), vz = bf2f(u.z), vw = bf2f(u.w);
    float s  = vx + vy + vz + vw;
    float sq = vx * vx + vy * vy + vz * vz + vw * vw;
    for (int off = 32; off > 0; off >>= 1) {
        s  += __shfl_down(s, off);
        sq += __shfl_down(sq, off);
    }
    const int wave = tid >> 6, lane = tid & 63;
    if (lane == 0) { ps[wave] = s; pq[wave] = sq; }
    __syncthreads();
    if (tid == 0) {
        float ts = ps[0] + ps[1] + ps[2] + ps[3];
        float tq = pq[0] + pq[1] + pq[2] + pq[3];
        float mu = ts * (1.0f / DMODEL);
        float var = tq * (1.0f / DMODEL) - mu * mu;
        ps[0] = mu;
        pq[0] = rsqrtf(var + 1e-5f);
    }
    __syncthreads();
    const float mu = ps[0], rs = pq[0];
    float4 g  = *reinterpret_cast<const float4*>(gamma + tid * 4);
    float4 be = *reinterpret_cast<const float4*>(beta + tid * 4);
    float4 o;
    o.x = g.x * (vx - mu) * rs + be.x;
    o.y = g.y * (vy - mu) * rs + be.y;
    o.z = g.z * (vz - mu) * rs + be.z;
    o.w = g.w * (vw - mu) * rs + be.w;
    *reinterpret_cast<float4*>(out + base) = o;
}

extern "C" void kernel_launch(void* const* d_in, const int* in_sizes, int n_in,
                              void* d_out, int out_size, void* d_ws, size_t ws_size,
                              hipStream_t stream)
{
    const float* dec   = (const float*)d_in[0];
    const float* pos   = (const float*)d_in[1];
    const float* mems  = (const float*)d_in[2];
    const float* gamma = (const float*)d_in[3];
    const float* beta  = (const float*)d_in[4];
    const int*   addp  = (const int*)d_in[5];
    float* out = (float*)d_out;

    // ws: catT bf16 [8192][2048] (32MB) | W bf16 [1024][2048] (4MB) | x bf16 (16MB)
    unsigned short* catT = (unsigned short*)d_ws;
    unsigned short* Wmat = catT + (size_t)NCOLS * KLEN;
    unsigned short* x    = Wmat + (size_t)QLEN * KLEN;

    prep_fused<<<dim3(32, 16, 9), 256, 0, stream>>>(dec, pos, mems, addp, catT, Wmat);
    gemm_band12<<<256, 512, 0, stream>>>(Wmat, catT, dec, x);
    layernorm_rows<<<8192, 256, 0, stream>>>(x, gamma, beta, out);
}

// Round 14
// 61.042 us; speedup vs baseline: 1.0965x; 1.0571x over previous
//
#include <hip/hip_runtime.h>
#include <hip/hip_bf16.h>

#define QLEN   1024
#define MLEN   1024
#define KLEN   2048
#define BATCH  8
#define DMODEL 1024
#define NCOLS  (BATCH * DMODEL)   // 8192
#define FTLEN  1025

#define BM 128
#define BN 256
#define BK 64
#define NT 18   // band: K in [m0, m0+1152), 18 tiles of 64

typedef __attribute__((ext_vector_type(4))) float f32x4;
typedef __attribute__((ext_vector_type(8))) short bf16x8;

typedef __attribute__((address_space(1))) const unsigned int as1_u32;
typedef __attribute__((address_space(3))) unsigned int as3_u32;

static __device__ __forceinline__ unsigned short f2bf(float f) {
    unsigned int u = __builtin_bit_cast(unsigned int, f);
    return (unsigned short)((u + 0x7fffu + ((u >> 16) & 1u)) >> 16);
}
static __device__ __forceinline__ float bf2f(unsigned short s) {
    return __builtin_bit_cast(float, (unsigned int)s << 16);
}
static __device__ __forceinline__ unsigned int packbf(float lo, float hi) {
    return (unsigned int)f2bf(lo) | ((unsigned int)f2bf(hi) << 16);
}

// ---------------------------------------------------------------------------
// Kernel 1: z<8  : cat = concat(mems, dec) (+ pos_emb), bf16, TRANSPOSED ->
//                  catT[n][k] (pair-packed u32 LDS transpose).
//           z==8 : fill W[m][k] = cos band matrix (fused launch).
// ---------------------------------------------------------------------------
__global__ __launch_bounds__(256) void prep_fused(
    const float* __restrict__ dec, const float* __restrict__ pos,
    const float* __restrict__ mems, const int* __restrict__ addp,
    unsigned short* __restrict__ catT, unsigned short* __restrict__ W)
{
    const int tid = threadIdx.x;
    if (blockIdx.z == 8) {
        const int bchunk = (blockIdx.y * 32 + blockIdx.x) * 4;
#pragma unroll
        for (int r = 0; r < 4; ++r) {
            const int idx = (bchunk + r) * 256 + tid;
            const int m = idx >> 9;
            const int k4 = (idx & 511) * 4;
            union { unsigned short s[4]; int2 v; } u;
#pragma unroll
            for (int j = 0; j < 4; ++j) {
                const int k = k4 + j;
                const int t = k - m;
                float w = 0.0f;
                if (t >= 0 && t < FTLEN) {
                    const int rr = (m * t) % FTLEN;
                    const float x = (float)rr * (1.0f / (float)FTLEN);  // revolutions
                    float c;
                    asm("v_cos_f32 %0, %1" : "=v"(c) : "v"(x));
                    w = c * 0.03123475237772121f;   // 1/sqrt(1025)
                }
                u.s[j] = f2bf(w);
            }
            *reinterpret_cast<int2*>(&W[(size_t)m * KLEN + k4]) = u.v;
        }
        return;
    }

    __shared__ unsigned int T2[32 * 68];   // 8704 B, stride 68 u32
    const int lt = blockIdx.x, dt = blockIdx.y, b = blockIdx.z;
    const int l0 = lt * 64, d0 = dt * 64;
    const int add_position = addp[0];

    const int dloc  = (tid & 15) * 4;   // 0..60
    const int lhalf = tid >> 4;         // 0..15

    float4 vc[2][2];
#pragma unroll
    for (int p = 0; p < 2; ++p)
#pragma unroll
        for (int jl = 0; jl < 2; ++jl) {
            const int l = l0 + p * 32 + lhalf * 2 + jl;
            const float* src = (l < MLEN)
                ? (mems + (size_t)l * NCOLS + b * DMODEL + d0 + dloc)
                : (dec + (size_t)(l - MLEN) * NCOLS + b * DMODEL + d0 + dloc);
            vc[p][jl] = *reinterpret_cast<const float4*>(src);
        }
    if (add_position) {
#pragma unroll
        for (int p = 0; p < 2; ++p)
#pragma unroll
            for (int jl = 0; jl < 2; ++jl) {
                const int l = l0 + p * 32 + lhalf * 2 + jl;
                float4 pv = *reinterpret_cast<const float4*>(
                    pos + (size_t)l * DMODEL + d0 + dloc);
                vc[p][jl].x += pv.x; vc[p][jl].y += pv.y;
                vc[p][jl].z += pv.z; vc[p][jl].w += pv.w;
            }
    }
#pragma unroll
    for (int p = 0; p < 2; ++p) {
        const int lp = p * 16 + lhalf;   // 0..31
        uint4 w;
        w.x = packbf(vc[p][0].x, vc[p][1].x);
        w.y = packbf(vc[p][0].y, vc[p][1].y);
        w.z = packbf(vc[p][0].z, vc[p][1].z);
        w.w = packbf(vc[p][0].w, vc[p][1].w);
        *reinterpret_cast<uint4*>(&T2[lp * 68 + dloc]) = w;
    }
    __syncthreads();
    const int d = tid >> 2;              // 0..63
    const size_t n = (size_t)b * DMODEL + d0 + d;
#pragma unroll
    for (int q = 0; q < 2; ++q) {
        const int c8 = (tid & 3) + 4 * q;    // 0..7
        uint4 o;
        o.x = T2[(c8 * 4 + 0) * 68 + d];
        o.y = T2[(c8 * 4 + 1) * 68 + d];
        o.z = T2[(c8 * 4 + 2) * 68 + d];
        o.w = T2[(c8 * 4 + 3) * 68 + d];
        *reinterpret_cast<uint4*>(&catT[n * KLEN + l0 + c8 * 8]) = o;
    }
}

// ---------------------------------------------------------------------------
// Kernel 2: banded GEMM — R11's verified-best minimal-sync loop: one
// s_barrier + one counted vmcnt(6) per K-tile, staging split 3+3 into the
// phase bodies (compiler-interleaved), T2 both-sides XOR swizzle, triple-
// buffered LDS, setprio around MFMA. Epilogue fuses the residual:
// x = bf16(dec + acc/sqrt(2048)).
// ---------------------------------------------------------------------------
__global__ __launch_bounds__(512) void gemm_band10(
    const unsigned short* __restrict__ W,     // [1024][2048]
    const unsigned short* __restrict__ catT,  // [8192][2048]
    const float* __restrict__ dec,            // [1024][8192]
    unsigned short* __restrict__ xout)        // bf16 [1024][8192]
{
    __shared__ unsigned short Alds[3][BM * BK];   // 3 x 16KB
    __shared__ unsigned short Blds[3][BN * BK];   // 3 x 32KB  (total 144KB)

    const int tid = threadIdx.x;
    const int wave = tid >> 6, lane = tid & 63;

    const int bid = blockIdx.x;
    const int xcd = bid & 7;
    const int kk = bid >> 3;              // 0..31
    const int m_idx = kk >> 2;            // 0..7
    const int n_idx = xcd * 4 + (kk & 3); // 0..31
    const int m0 = m_idx * BM, n0 = n_idx * BN;
    const int wm = wave >> 2, wn = wave & 3;   // 2 x 4 wave grid

    f32x4 acc[4][4];
    for (int i = 0; i < 4; ++i)
        for (int j = 0; j < 4; ++j)
            acc[i][j] = (f32x4){0.f, 0.f, 0.f, 0.f};

    const int srow = tid >> 3;           // 0..63
    const int scol = (((tid & 7) ^ ((tid >> 3) & 7)) * 8);  // pre-swizzled src col
    const int fr = lane & 15;
    const int kg = lane >> 4;
    const int rswz = (fr & 7) * 8;       // read-side XOR (elements)

#define STAGE_LOAD_A(S, T, P) do {                                              \
    const int k0_ = m0 + (T) * BK;                                              \
    const int row = (P) * 64 + srow;                                            \
    __builtin_amdgcn_global_load_lds(                                           \
        (as1_u32*)(const void*)(W + (size_t)(m0 + row) * KLEN + k0_ + scol),    \
        (as3_u32*)(void*)(&Alds[S][row * BK + scol]), 16, 0, 0);                \
} while (0)
#define STAGE_LOAD_B(S, T, P) do {                                              \
    const int k0_ = m0 + (T) * BK;                                              \
    const int row = (P) * 64 + srow;                                            \
    __builtin_amdgcn_global_load_lds(                                           \
        (as1_u32*)(const void*)(catT + (size_t)(n0 + row) * KLEN + k0_ + scol), \
        (as3_u32*)(void*)(&Blds[S][row * BK + scol]), 16, 0, 0);                \
} while (0)
#define STAGE_ALL(S, T) do {                                                    \
    STAGE_LOAD_A(S, T, 0); STAGE_LOAD_A(S, T, 1);                               \
    STAGE_LOAD_B(S, T, 0); STAGE_LOAD_B(S, T, 1);                               \
    STAGE_LOAD_B(S, T, 2); STAGE_LOAD_B(S, T, 3);                               \
} while (0)

    STAGE_ALL(0, 0);
    STAGE_ALL(1, 1);

    for (int t = 0; t < NT; ++t) {
        if (t == NT - 1)
            asm volatile("s_waitcnt vmcnt(0)" ::: "memory");
        else
            asm volatile("s_waitcnt vmcnt(6)" ::: "memory");
        __builtin_amdgcn_s_barrier();

        const unsigned short* Ab = Alds[t % 3];
        const unsigned short* Bb = Blds[t % 3];
        const int s2 = (t + 2) % 3;
        const bool pf = (t + 2 < NT);

        // ---------------- phase 0 (ks = 0) ----------------
        {
            bf16x8 a[4], b[4];
#pragma unroll
            for (int f = 0; f < 4; ++f)
                a[f] = *reinterpret_cast<const bf16x8*>(
                    Ab + (wm * 64 + f * 16 + fr) * BK + ((kg * 8) ^ rswz));
#pragma unroll
            for (int f = 0; f < 4; ++f)
                b[f] = *reinterpret_cast<const bf16x8*>(
                    Bb + (wn * 64 + f * 16 + fr) * BK + ((kg * 8) ^ rswz));
            if (pf) { STAGE_LOAD_A(s2, t + 2, 0); STAGE_LOAD_B(s2, t + 2, 0); STAGE_LOAD_B(s2, t + 2, 1); }
            __builtin_amdgcn_s_setprio(1);
#pragma unroll
            for (int fm = 0; fm < 4; ++fm)
#pragma unroll
                for (int fn = 0; fn < 4; ++fn)
                    acc[fm][fn] = __builtin_amdgcn_mfma_f32_16x16x32_bf16(
                        a[fm], b[fn], acc[fm][fn], 0, 0, 0);
            __builtin_amdgcn_s_setprio(0);
        }
        // ---------------- phase 1 (ks = 1) ----------------
        {
            bf16x8 a[4], b[4];
#pragma unroll
            for (int f = 0; f < 4; ++f)
                a[f] = *reinterpret_cast<const bf16x8*>(
                    Ab + (wm * 64 + f * 16 + fr) * BK + ((32 + kg * 8) ^ rswz));
#pragma unroll
            for (int f = 0; f < 4; ++f)
                b[f] = *reinterpret_cast<const bf16x8*>(
                    Bb + (wn * 64 + f * 16 + fr) * BK + ((32 + kg * 8) ^ rswz));
            if (pf) { STAGE_LOAD_A(s2, t + 2, 1); STAGE_LOAD_B(s2, t + 2, 2); STAGE_LOAD_B(s2, t + 2, 3); }
            __builtin_amdgcn_s_setprio(1);
#pragma unroll
            for (int fm = 0; fm < 4; ++fm)
#pragma unroll
                for (int fn = 0; fn < 4; ++fn)
                    acc[fm][fn] = __builtin_amdgcn_mfma_f32_16x16x32_bf16(
                        a[fm], b[fn], acc[fm][fn], 0, 0, 0);
            __builtin_amdgcn_s_setprio(0);
        }
    }
#undef STAGE_ALL
#undef STAGE_LOAD_A
#undef STAGE_LOAD_B

    // epilogue: x = bf16(dec + acc/sqrt(2048)); C/D: col=lane&15, row=(lane>>4)*4+j
    const float inv = 0.022097086912079612f;  // 1/sqrt(2048)
    const int col16 = lane & 15, rquad = lane >> 4;
#pragma unroll
    for (int fm = 0; fm < 4; ++fm)
#pragma unroll
        for (int fn = 0; fn < 4; ++fn)
#pragma unroll
            for (int j = 0; j < 4; ++j) {
                const int m = m0 + wm * 64 + fm * 16 + rquad * 4 + j;
                const int n = n0 + wn * 64 + fn * 16 + col16;
                const size_t o = (size_t)m * NCOLS + n;
                xout[o] = f2bf(dec[o] + acc[fm][fn][j] * inv);
            }
}

// ---------------------------------------------------------------------------
// Kernel 3: out = LayerNorm(x) over d=1024 per (m,b) row. x bf16 (residual
// already applied), out f32. 48 MB traffic.
// ---------------------------------------------------------------------------
__global__ __launch_bounds__(256) void layernorm_rows(
    const unsigned short* __restrict__ x,
    const float* __restrict__ gamma, const float* __restrict__ beta,
    float* __restrict__ out)
{
    __shared__ float ps[4], pq[4];
    const int row = blockIdx.x;
    const int tid = threadIdx.x;
    const size_t base = (size_t)row * DMODEL + tid * 4;
    ushort4 u = *reinterpret_cast<const ushort4*>(x + base);
    float vx = bf2f(u.x), vy = bf2f(u.y), vz = bf2f(u.z), vw = bf2f(u.w);
    float s  = vx + vy + vz + vw;
    float sq = vx * vx + vy * vy + vz * vz + vw * vw;
    for (int off = 32; off > 0; off >>= 1) {
        s  += __shfl_down(s, off);
        sq += __shfl_down(sq, off);
    }
    const int wave = tid >> 6, lane = tid & 63;
    if (lane == 0) { ps[wave] = s; pq[wave] = sq; }
    __syncthreads();
    if (tid == 0) {
        float ts = ps[0] + ps[1] + ps[2] + ps[3];
        float tq = pq[0] + pq[1] + pq[2] + pq[3];
        float mu = ts * (1.0f / DMODEL);
        float var = tq * (1.0f / DMODEL) - mu * mu;
        ps[0] = mu;
        pq[0] = rsqrtf(var + 1e-5f);
    }
    __syncthreads();
    const float mu = ps[0], rs = pq[0];
    float4 g  = *reinterpret_cast<const float4*>(gamma + tid * 4);
    float4 be = *reinterpret_cast<const float4*>(beta + tid * 4);
    float4 o;
    o.x = g.x * (vx - mu) * rs + be.x;
    o.y = g.y * (vy - mu) * rs + be.y;
    o.z = g.z * (vz - mu) * rs + be.z;
    o.w = g.w * (vw - mu) * rs + be.w;
    *reinterpret_cast<float4*>(out + base) = o;
}

extern "C" void kernel_launch(void* const* d_in, const int* in_sizes, int n_in,
                              void* d_out, int out_size, void* d_ws, size_t ws_size,
                              hipStream_t stream)
{
    const float* dec   = (const float*)d_in[0];
    const float* pos   = (const float*)d_in[1];
    const float* mems  = (const float*)d_in[2];
    const float* gamma = (const float*)d_in[3];
    const float* beta  = (const float*)d_in[4];
    const int*   addp  = (const int*)d_in[5];
    float* out = (float*)d_out;

    // ws: catT bf16 [8192][2048] (32MB) | W bf16 [1024][2048] (4MB) | x bf16 (16MB)
    unsigned short* catT = (unsigned short*)d_ws;
    unsigned short* Wmat = catT + (size_t)NCOLS * KLEN;
    unsigned short* x    = Wmat + (size_t)QLEN * KLEN;

    prep_fused<<<dim3(32, 16, 9), 256, 0, stream>>>(dec, pos, mems, addp, catT, Wmat);
    gemm_band10<<<256, 512, 0, stream>>>(Wmat, catT, dec, x);
    layernorm_rows<<<8192, 256, 0, stream>>>(x, gamma, beta, out);
}